// Round 6
// baseline (474.801 us; speedup 1.0000x reference)
//
#include <hip/hip_runtime.h>

// ConvLSTM B=8,T=16,CIN=16,HID=64,H=W=64,K=3 'SAME' — 16-launch bf16 MFMA.
// R5 lesson: every block reads the whole Wfrag (~400KB) -> B traffic scales
// with block count; 1024 half-row blocks = ~410MB/step of L2 traffic (~12us).
// R6: full-row blocks (512), 3 blocks/CU, depth-2 B prefetch (flat unrolled
// 27-iter K-loop, 3-slot circular B buffer). Bias folded as channel 80,
// o-gate at center tap only, x pre-converted bf16 ch-last, c in place.

#define B_ 8
#define T_ 16
#define CIN_ 16
#define HID_ 64
#define H_ 64
#define W_ 64
#define HW_ (H_*W_)
#define CTOT_ 80
#define XS_ROW 66                 // 64 px + 2 halo
#define XS_CH 104                 // 96 K-ch + bias + pad; 52-word stride -> 2-way banks (free)
#define XS_SIZE (3*XS_ROW*XS_CH)  // 20592 hw = 41184 B -> 3 blocks/CU
#define CSTRIDE_ (B_*HID_*HW_)    // 2097152

typedef __attribute__((ext_vector_type(8))) short short8;
typedef __attribute__((ext_vector_type(4))) float f32x4;

__device__ __forceinline__ unsigned short f2bf(float f){
    unsigned u = __float_as_uint(f);
    u = (u + 0x7FFFu + ((u >> 16) & 1u)) >> 16;   // RNE
    return (unsigned short)u;
}
__device__ __forceinline__ float sigm_(float v){ return 1.0f/(1.0f + __expf(-v)); }
__device__ __forceinline__ float tanh_(float v){ return 2.0f/(1.0f + __expf(-2.0f*v)) - 1.0f; }

// Wfrag: [tap 9][cc 3][ng 16] frags of 512 hw ([lane][j]).
// n = ng*16+(lane&15): g=n>>6, o=n&63; k-ch c = cc*32+(lane>>4)*8+j.
// Bias folded at c==80 (constant-1 A channel), center tap only.
__global__ void prep_wfrag(const float* __restrict__ Wf, const float* __restrict__ Wi,
                           const float* __restrict__ Wc, const float* __restrict__ Wo,
                           const float* __restrict__ bf, const float* __restrict__ bi,
                           const float* __restrict__ bc, const float* __restrict__ bo,
                           unsigned short* __restrict__ Wfrag){
    int idx = blockIdx.x*256 + threadIdx.x;          // 864*256 = 221184 exact
    int j    = idx & 7;
    int lane = (idx >> 3) & 63;
    int frag = idx >> 9;
    int ng = frag & 15;
    int tc = frag >> 4;
    int cc = tc % 3, tap = tc / 3;
    int n = ng*16 + (lane & 15);
    int g = n >> 6, o = n & 63;
    int c = cc*32 + ((lane >> 4) << 3) + j;
    int ky = tap / 3, kx = tap % 3;
    float v = 0.0f;
    if (c < CTOT_){
        if (g == 0)      v = Wf[((o*CTOT_ + c)*3 + ky)*3 + kx];
        else if (g == 1) v = Wi[((o*CTOT_ + c)*3 + ky)*3 + kx];
        else if (g == 2) v = Wc[((o*CTOT_ + c)*3 + ky)*3 + kx];
        else             v = (tap == 4) ? Wo[o*CTOT_ + c] : 0.0f;
    } else if (c == CTOT_ && tap == 4){              // bias channel
        v = (g==0) ? bf[o] : (g==1) ? bi[o] : (g==2) ? bc[o] : bo[o];
    }
    Wfrag[idx] = f2bf(v);
}

// x[b][t][c][y][px] fp32 -> xbf[b][t][y][px][c16] bf16
__global__ void prep_xbf(const float* __restrict__ x, unsigned short* __restrict__ xbf){
    int idx = blockIdx.x*256 + threadIdx.x;          // 524288 = (b,t,y,px) flat
    int px = idx & 63;
    int y  = (idx >> 6) & 63;
    int bt = idx >> 12;
    const float* src = x + (size_t)bt*CIN_*HW_ + y*W_ + px;
    unsigned short tmp[16];
    #pragma unroll
    for (int c = 0; c < 16; ++c) tmp[c] = f2bf(src[(size_t)c*HW_]);
    uint4* dst = (uint4*)(xbf + (size_t)idx*16);
    dst[0] = *(uint4*)(tmp);
    dst[1] = *(uint4*)(tmp + 8);
}

__global__ __launch_bounds__(256, 3) void lstm_step(
    const unsigned short* __restrict__ xbf,
    const unsigned short* __restrict__ Wfrag,
    float* __restrict__ cbuf,                        // [b][y][px][o] fp32, in place
    const unsigned short* __restrict__ hin,          // [b][y][px][o] bf16
    unsigned short* __restrict__ hout,
    float* __restrict__ out,                         // [h|c] std layout, t==15 only
    int t)
{
    __shared__ __align__(16) unsigned short Xs[XS_SIZE];
    const int id   = blockIdx.x;
    // XCD swizzle: id&7 -> XCD; contiguous 8-row y band per XCD for halo locality.
    const int xcd  = id & 7;
    const int jj   = id >> 3;
    const int y    = xcd*8 + (jj & 7);
    const int b    = (jj >> 3) & 7;
    const int tid  = threadIdx.x;
    const int lane = tid & 63;
    const int w    = tid >> 6;
    const int l15  = lane & 15;
    const int q    = lane >> 4;

    // ---- zero LDS (SAME-pad borders, pad channels; garbage could be NaN-coded)
    uint4 z4; z4.x=z4.y=z4.z=z4.w=0u;
    for (int i = tid; i < XS_SIZE/8; i += 256) ((uint4*)Xs)[i] = z4;
    __syncthreads();

    // ---- stage x: 3 rows x 66 px x 2 ch8 = 396 uint4
    for (int i = tid; i < 396; i += 256){
        int row = i/132, rem = i - row*132;
        int px = rem >> 1, ch8 = rem & 1;
        int yy = y + row - 1, pxg = px - 1;
        if (yy >= 0 && yy < H_ && pxg >= 0 && pxg < W_){
            uint4 v = *(const uint4*)(xbf + ((((size_t)(b*T_ + t)*H_ + yy)*W_ + pxg)*16 + ch8*8));
            *(uint4*)(Xs + (row*XS_ROW + px)*XS_CH + ch8*8) = v;
        }
    }
    // ---- stage h: 3 x 66 x 8 = 1584 uint4 (t==0: stays zero)
    if (t > 0){
        for (int i = tid; i < 1584; i += 256){
            int row = i/528, rem = i - row*528;
            int px = rem >> 3, ch8 = rem & 7;
            int yy = y + row - 1, pxg = px - 1;
            if (yy >= 0 && yy < H_ && pxg >= 0 && pxg < W_){
                uint4 v = *(const uint4*)(hin + ((((size_t)b*H_ + yy)*W_ + pxg)*HID_ + ch8*8));
                *(uint4*)(Xs + (row*XS_ROW + px)*XS_CH + CIN_ + ch8*8) = v;
            }
        }
    }
    // ---- constant-1 bias channel (ch 80)
    for (int i = tid; i < 3*XS_ROW; i += 256)
        Xs[i*XS_CH + CTOT_] = 0x3F80;                // bf16 1.0
    __syncthreads();

    // ---- K-loop: flat 27 iters, fully unrolled; depth-2 B prefetch, depth-1 A
    f32x4 acc[4][4];
    #pragma unroll
    for (int g = 0; g < 4; ++g)
        #pragma unroll
        for (int mf = 0; mf < 4; ++mf) acc[g][mf] = (f32x4)0.0f;

    short8 aC[4], bq[3][3], bqo[2];
    {   // preload A(0) and B(0), B(1)
        const unsigned short* ap = Xs + (size_t)l15*XS_CH + q*8;   // ky=0,kx=0,cc=0
        #pragma unroll
        for (int mf = 0; mf < 4; ++mf) aC[mf] = *(const short8*)(ap + (size_t)mf*16*XS_CH);
        #pragma unroll
        for (int kt = 0; kt < 2; ++kt){
            const unsigned short* bp = Wfrag + ((size_t)(kt*3*16 + w) << 9) + lane*8;
            #pragma unroll
            for (int g = 0; g < 3; ++g) bq[kt][g] = *(const short8*)(bp + ((size_t)g << 11));
        }
    }
    #pragma unroll
    for (int kt = 0; kt < 27; ++kt){
        const int tap = kt % 9, cc = kt / 9;
        // prefetch B(kt+2)
        if (kt + 2 < 27){
            const int pk = kt + 2, pt = pk % 9, pc = pk / 9;
            const unsigned short* bp = Wfrag + ((size_t)((pt*3 + pc)*16 + w) << 9) + lane*8;
            #pragma unroll
            for (int g = 0; g < 3; ++g) bq[pk % 3][g] = *(const short8*)(bp + ((size_t)g << 11));
            if (pt == 4)
                bqo[pc & 1] = *(const short8*)(Wfrag + ((size_t)((4*3 + pc)*16 + 12 + w) << 9) + lane*8);
        }
        // prefetch A(kt+1) from LDS
        short8 aN[4];
        if (kt + 1 < 27){
            const int nk = kt + 1, nt = nk % 9, nc = nk / 9;
            const int nky = nt / 3, nkx = nt % 3;
            const unsigned short* ap =
                Xs + (size_t)(nky*XS_ROW + l15 + nkx)*XS_CH + nc*32 + q*8;
            #pragma unroll
            for (int mf = 0; mf < 4; ++mf) aN[mf] = *(const short8*)(ap + (size_t)mf*16*XS_CH);
        }
        // MFMAs for kt
        if (tap == 4){
            #pragma unroll
            for (int mf = 0; mf < 4; ++mf)
                acc[3][mf] = __builtin_amdgcn_mfma_f32_16x16x32_bf16(aC[mf], bqo[cc & 1], acc[3][mf], 0,0,0);
        }
        #pragma unroll
        for (int g = 0; g < 3; ++g)
            #pragma unroll
            for (int mf = 0; mf < 4; ++mf)
                acc[g][mf] = __builtin_amdgcn_mfma_f32_16x16x32_bf16(aC[mf], bq[kt % 3][g], acc[g][mf], 0,0,0);
        if (kt + 1 < 27){
            #pragma unroll
            for (int mf = 0; mf < 4; ++mf) aC[mf] = aN[mf];
        }
    }

    // ---- epilogue: wave-local gates; c in place, channel-last
    const int o = w*16 + l15;
    #pragma unroll
    for (int mf = 0; mf < 4; ++mf){
        #pragma unroll
        for (int r = 0; r < 4; ++r){
            const int m = mf*16 + q*4 + r;                 // global pixel x
            const float fv = sigm_(acc[0][mf][r]);
            const float iv = sigm_(acc[1][mf][r]);
            const float gv = tanh_(acc[2][mf][r]);
            const float ov = sigm_(acc[3][mf][r]);
            const size_t cidx = (((size_t)(b*H_ + y)*W_ + m)*HID_ + o);
            const float cprev = t ? cbuf[cidx] : 0.0f;
            const float cn = cprev*fv + iv*gv;
            const float hn = tanh_(cn)*ov;
            if (t < T_-1){
                cbuf[cidx] = cn;
                hout[cidx] = f2bf(hn);
            } else {
                const size_t oidx = ((((size_t)(b*HID_ + o))*H_ + y)*W_ + m);
                out[oidx] = hn;
                out[CSTRIDE_ + oidx] = cn;
            }
        }
    }
}

extern "C" void kernel_launch(void* const* d_in, const int* in_sizes, int n_in,
                              void* d_out, int out_size, void* d_ws, size_t ws_size,
                              hipStream_t stream){
    const float* x  = (const float*)d_in[0];
    const float* Wf = (const float*)d_in[1];
    const float* bf = (const float*)d_in[2];
    const float* Wi = (const float*)d_in[3];
    const float* bi = (const float*)d_in[4];
    const float* Wc = (const float*)d_in[5];
    const float* bc = (const float*)d_in[6];
    const float* Wo = (const float*)d_in[7];
    const float* bo = (const float*)d_in[8];

    // ws: Wfrag 442368 | xbf 16777216 | cbuf 8388608 | hbfA 4194304 | hbfB 4194304
    unsigned short* Wfrag = (unsigned short*)d_ws;
    unsigned short* xbf   = (unsigned short*)((char*)d_ws + 442368);
    float*          cbuf  = (float*)((char*)d_ws + 442368 + 16777216);
    unsigned short* hbfA  = (unsigned short*)((char*)d_ws + 442368 + 16777216 + 8388608);
    unsigned short* hbfB  = hbfA + CSTRIDE_;

    prep_wfrag<<<dim3(864), dim3(256), 0, stream>>>(Wf, Wi, Wc, Wo, bf, bi, bc, bo, Wfrag);
    prep_xbf<<<dim3(2048), dim3(256), 0, stream>>>(x, xbf);

    for (int t = 0; t < T_; ++t){
        const unsigned short* hi = (t & 1) ? hbfA : hbfB;   // t==0 never reads
        unsigned short*       ho = (t & 1) ? hbfB : hbfA;
        lstm_step<<<dim3(512), dim3(256), 0, stream>>>(
            xbf, Wfrag, cbuf, hi, ho, (float*)d_out, t);
    }
}